// Round 7
// baseline (447.103 us; speedup 1.0000x reference)
//
#include <hip/hip_runtime.h>
#include <stdint.h>

#define Bn 32
#define Nn 1723
#define Cn 512
#define Hn 256
#define MTA 54    // ceil(1723/32): stage-A tiles == supT sub-steps
#define MTB 27    // ceil(1723/64): stage-B row tiles

typedef __bf16 bf16x8 __attribute__((ext_vector_type(8)));
typedef float f32x4 __attribute__((ext_vector_type(4)));
typedef unsigned short u16;

__device__ __forceinline__ u16 f2b(float f){
  union{float f; uint32_t i;} c; c.f=f; uint32_t u=c.i;
  u += 0x7fffu + ((u>>16)&1u);
  return (u16)(u>>16);
}
__device__ __forceinline__ bf16x8 ld8(const u16* p){
  union{ uint4 u; bf16x8 b; } c;
  c.u = *reinterpret_cast<const uint4*>(p);
  return c.b;
}
__device__ __forceinline__ f32x4 mfma16(bf16x8 a, bf16x8 b, f32x4 c){
  return __builtin_amdgcn_mfma_f32_16x16x32_bf16(a,b,c,0,0,0);
}
// lgkmcnt-only barrier: LDS writes visible, global loads stay in flight.
#define BAR() do{ asm volatile("s_waitcnt lgkmcnt(0)" ::: "memory"); \
                  __builtin_amdgcn_s_barrier(); \
                  asm volatile("" ::: "memory"); }while(0)

// ---- kernel 0: weights -> bf16 MFMA-fragment-major (validated R5) ----
__global__ __launch_bounds__(256) void k_prep(
    const float* __restrict__ W1, const float* __restrict__ Wc, const float* __restrict__ W2,
    u16* __restrict__ W1f, u16* __restrict__ WcTf, u16* __restrict__ W2f)
{
  const int t = blockIdx.x*256 + threadIdx.x;
  const int lane = t & 63, unit = t >> 6;
  const int lr = lane & 15, lh = lane >> 4;
  const float* src; u16* dst; int K, tile, kk; bool tr = false;
  if (unit < 256){ tile = unit>>4; kk = unit&15; src = W1; dst = W1f; K = 512; }
  else if (unit < 384){ int u = unit-256; tile = u>>3; kk = u&7; src = Wc; dst = WcTf; K = 256; tr = true; }
  else { int u = unit-384; tile = u>>3; kk = u&7; src = W2; dst = W2f; K = 256; }
  const int row = tile*16 + lr;
  const int k0 = kk*32 + lh*8;
  union{u16 s[8]; uint4 u;} o;
  #pragma unroll
  for (int j=0;j<8;++j){
    float v = tr ? src[(size_t)(k0+j)*256 + row] : src[(size_t)row*K + k0 + j];
    o.s[j] = f2b(v);
  }
  *reinterpret_cast<uint4*>(dst + (size_t)(tile*(K/32)+kk)*512 + lane*8) = o.u;
}

// ---------------- stage A (unchanged, validated R5) ----------------
__global__ __launch_bounds__(256) void k_stageA(
    const float* __restrict__ x, const float* __restrict__ prw, const float* __restrict__ prb,
    const u16* __restrict__ W1f, const float* __restrict__ b1,
    const float* __restrict__ n1w, const float* __restrict__ n1b,
    const u16* __restrict__ WcTf, u16* __restrict__ supT)
{
  __shared__ u16 t1[32*512];
  __shared__ float ps[2][32], pq[2][32];
  u16* const t2 = t1;
  const int b = blockIdx.y;
  const int m0 = blockIdx.x*32;
  const int tid = threadIdx.x;
  const int w = tid>>6, l = tid&63, lr = l&15, lh = l>>4;
  const int wm = w>>1, wn = w&1;

  float pw[8], pb[8];
  #pragma unroll
  for (int j=0;j<8;++j){ pw[j]=prw[l*8+j]; pb[j]=prb[l*8+j]; }
  #pragma unroll
  for (int rr=0; rr<8; ++rr){
    const int rloc = w*8+rr;
    int rg = m0 + rloc; rg = rg < Nn ? rg : Nn-1;
    const float* src = x + ((size_t)b*Nn + rg)*Cn + l*8;
    float4 c0 = *reinterpret_cast<const float4*>(src);
    float4 c1 = *reinterpret_cast<const float4*>(src+4);
    float v[8] = {c0.x,c0.y,c0.z,c0.w,c1.x,c1.y,c1.z,c1.w};
    float s=0.f, q=0.f;
    #pragma unroll
    for (int j=0;j<8;++j){ s+=v[j]; q+=v[j]*v[j]; }
    #pragma unroll
    for (int m=1;m<64;m<<=1){ s += __shfl_xor(s,m); q += __shfl_xor(q,m); }
    const float mean = s*(1.f/Cn);
    const float rstd = rsqrtf(fmaxf(q*(1.f/Cn) - mean*mean, 0.f) + 1e-12f);
    union{uint4 u; u16 s[8];} ov;
    #pragma unroll
    for (int j=0;j<8;++j){
      float t = (v[j]-mean)*rstd*pw[j] + pb[j];
      ov.s[j] = f2b(fmaxf(t,0.f));
    }
    const int idx = (rloc*512 + l*8) ^ ((rloc&7)<<3);
    *reinterpret_cast<uint4*>(&t1[idx]) = ov.u;
  }
  __syncthreads();

  f32x4 acc[8];
  #pragma unroll
  for (int i=0;i<8;++i) acc[i] = f32x4{0.f,0.f,0.f,0.f};
  const int arow = wm*16 + lr;
  const int aswz = (arow&7)<<3;
  for (int kk=0; kk<16; ++kk){
    bf16x8 a = ld8(&t1[(arow*512 + kk*32 + lh*8) ^ aswz]);
    #pragma unroll
    for (int nt=0; nt<8; ++nt){
      bf16x8 bb = ld8(W1f + (size_t)(((wn*8+nt)*16 + kk))*512 + l*8);
      acc[nt] = mfma16(a, bb, acc[nt]);
    }
  }

  float sum[4]={0,0,0,0}, sq[4]={0,0,0,0};
  #pragma unroll
  for (int nt=0; nt<8; ++nt){
    const float bias = b1[wn*128+nt*16+lr];
    #pragma unroll
    for (int r=0;r<4;++r){
      float vv = acc[nt][r] + bias;
      acc[nt][r] = vv; sum[r]+=vv; sq[r]+=vv*vv;
    }
  }
  #pragma unroll
  for (int m=1;m<16;m<<=1){
    #pragma unroll
    for (int r=0;r<4;++r){ sum[r]+=__shfl_xor(sum[r],m); sq[r]+=__shfl_xor(sq[r],m); }
  }
  if (lr==0){
    #pragma unroll
    for (int r=0;r<4;++r){
      const int row = wm*16 + lh*4 + r;
      ps[wn][row]=sum[r]; pq[wn][row]=sq[r];
    }
  }
  __syncthreads();
  float mean[4], rstd[4];
  #pragma unroll
  for (int r=0;r<4;++r){
    const int row = wm*16 + lh*4 + r;
    const float S = ps[0][row]+ps[1][row];
    const float Q = pq[0][row]+pq[1][row];
    const float mu = S*(1.f/Hn);
    mean[r] = mu;
    rstd[r] = rsqrtf(fmaxf(Q*(1.f/Hn) - mu*mu, 0.f) + 1e-12f);
  }
  #pragma unroll
  for (int nt=0; nt<8; ++nt){
    const int col = wn*128+nt*16+lr;
    const float nw = n1w[col], nb = n1b[col];
    #pragma unroll
    for (int r=0;r<4;++r){
      const int row = wm*16 + lh*4 + r;
      float t = (acc[nt][r]-mean[r])*rstd[r]*nw + nb;
      t2[(row*256 + col) ^ ((row&7)<<3)] = f2b(fmaxf(t,0.f));
    }
  }
  __syncthreads();

  f32x4 acc2[8];
  #pragma unroll
  for (int i=0;i<8;++i) acc2[i] = f32x4{0.f,0.f,0.f,0.f};
  for (int kk=0; kk<8; ++kk){
    bf16x8 a = ld8(&t2[(arow*256 + kk*32 + lh*8) ^ aswz]);
    #pragma unroll
    for (int nt=0; nt<8; ++nt){
      bf16x8 bb = ld8(WcTf + (size_t)(((wn*8+nt)*8 + kk))*512 + l*8);
      acc2[nt] = mfma16(a, bb, acc2[nt]);
    }
  }

  const int off512 = (wm*2 + (lh>>1))*128 + lr*8 + (lh&1)*4;
  #pragma unroll
  for (int nt=0; nt<8; ++nt){
    const int htile = wn*8 + nt;
    const size_t base = ((size_t)(b*16 + htile)*MTA + blockIdx.x)*512 + off512;
    ushort4 o;
    o.x = f2b(acc2[nt][0]); o.y = f2b(acc2[nt][1]);
    o.z = f2b(acc2[nt][2]); o.w = f2b(acc2[nt][3]);
    *reinterpret_cast<ushort4*>(supT + base) = o;
  }
}

// ---------------- stage B: consumption-ordered VMEM pipeline ----------------
// grid 864 (XCD-grouped b), block 256. K-step 64.
// Invariant: no load consumed in the phase it was issued -> all waits counted.
__global__ __launch_bounds__(256) void k_stageB(
    const float* __restrict__ adj, const u16* __restrict__ supT,
    const float* __restrict__ cb, const float* __restrict__ n2w, const float* __restrict__ n2b,
    const u16* __restrict__ W2f, const float* __restrict__ bl2,
    const float* __restrict__ x, float* __restrict__ out)
{
  __shared__ u16 smem[64*256];        // 32 KB: t3; first 16 KB doubles as atile[2][64*64]
  __shared__ float ps[4][64], pq[4][64];
  u16* const atile = smem;
  u16* const t3 = smem;
  const int bid = blockIdx.x;
  const int xcd = bid & 7, idx = bid >> 3;
  const int b = xcd*4 + (idx & 3);
  const int m0 = (idx >> 2) * 64;
  const int tid = threadIdx.x, w = tid>>6, l = tid&63, lr = l&15, lh = l>>4;
  const int sc2 = tid & 31, sr0 = tid >> 5;

  const float* adjb = adj + (size_t)b*Nn*Nn;
  const u16* supb = supT + (size_t)b*16*MTA*512;

  int srow[8];
  #pragma unroll
  for (int i=0;i<8;++i){ int rg = m0 + sr0 + 8*i; srow[i] = rg<Nn?rg:Nn-1; }

  float2 pfE[8], pfO[8];
  bf16x8 bv0r[4], bv1r[4];
  f32x4 acc1[4][4];
  #pragma unroll
  for (int i=0;i<4;++i)
    #pragma unroll
    for (int j=0;j<4;++j) acc1[i][j] = f32x4{0.f,0.f,0.f,0.f};

  // ---- pipeline building blocks ----
  #define ISSUE(pf, s) do{                                              \
    const int kg = (s)*64 + sc2*2;  /* loop steps <=25: always in-bounds */ \
    _Pragma("unroll")                                                   \
    for (int i=0;i<8;++i)                                               \
      pf[i] = *reinterpret_cast<const float2*>(adjb + (size_t)srow[i]*Nn + kg); \
  }while(0)

  #define ISSUE_TAIL(pf) do{      /* step 26: guarded scalar loads */   \
    const int kg = 26*64 + sc2*2;                                       \
    _Pragma("unroll")                                                   \
    for (int i=0;i<8;++i){                                              \
      const float* p = adjb + (size_t)srow[i]*Nn;                       \
      pf[i].x = (kg   < Nn) ? p[kg]   : 0.f;                            \
      pf[i].y = (kg+1 < Nn) ? p[kg+1] : 0.f;                            \
    }                                                                   \
  }while(0)

  #define COMMIT(pf, buf) do{                                           \
    _Pragma("unroll")                                                   \
    for (int i=0;i<8;++i){                                              \
      const int row = sr0 + 8*i;                                        \
      uint32_t pk;                                                      \
      asm("v_cvt_pk_bf16_f32 %0, %1, %2" : "=v"(pk) : "v"(pf[i].x), "v"(pf[i].y)); \
      *reinterpret_cast<uint32_t*>(&atile[(buf)*4096 + ((row*64 + sc2*2) ^ ((row&7)<<3))]) = pk; \
    }                                                                   \
  }while(0)

  #define BVLOAD(bvr, sub) do{                                          \
    _Pragma("unroll")                                                   \
    for (int nt=0;nt<4;++nt)                                            \
      bvr[nt] = ld8(supb + (size_t)((w*4+nt)*MTA + (sub))*512 + l*8);   \
  }while(0)

  #define MHALF(buf, half, bvr) do{                                     \
    _Pragma("unroll")                                                   \
    for (int mt=0;mt<4;++mt){                                           \
      const int row = mt*16+lr;                                         \
      bf16x8 a = ld8(&atile[(buf)*4096 + ((row*64 + (half)*32 + lh*8) ^ ((row&7)<<3))]); \
      _Pragma("unroll")                                                 \
      for (int nt=0;nt<4;++nt) acc1[mt][nt] = mfma16(a, bvr[nt], acc1[mt][nt]); \
    }                                                                   \
  }while(0)

  // ---- prologue: pf(0),pf(1),pf(2) + bv(step0) in flight; atile[0] committed ----
  ISSUE(pfE, 0);
  BVLOAD(bv0r, 0); BVLOAD(bv1r, 1);
  ISSUE(pfO, 1);
  COMMIT(pfE, 0);       // waits pfE only (bv+pfO younger, stay in flight)
  ISSUE(pfE, 2);
  BAR();

  // ---- main loop: 11 pairs, steps 0..21 (all issues in-bounds, maskless) ----
  for (int sp=0; sp<11; ++sp){
    const int s = 2*sp;
    // iter s (buf 0): consume bv(step s) + atile[0]; commit pf(s+1); issue pf(s+3)
    MHALF(0, 0, bv0r);  BVLOAD(bv0r, 2*s+2);
    MHALF(0, 1, bv1r);  BVLOAD(bv1r, 2*s+3);
    COMMIT(pfO, 1);     ISSUE(pfO, s+3);
    BAR();
    // iter s+1 (buf 1)
    MHALF(1, 0, bv0r);  BVLOAD(bv0r, 2*s+4);
    MHALF(1, 1, bv1r);  BVLOAD(bv1r, 2*s+5);
    COMMIT(pfE, 0);     ISSUE(pfE, s+4);
    BAR();
  }
  // ---- peeled iters 22..25 ----
  // iter 22 (buf 0): commit pf(23), issue pf(25)
  MHALF(0, 0, bv0r);  BVLOAD(bv0r, 46);
  MHALF(0, 1, bv1r);  BVLOAD(bv1r, 47);
  COMMIT(pfO, 1);     ISSUE(pfO, 25);
  BAR();
  // iter 23 (buf 1): commit pf(24), issue pf(26) (tail-masked loads)
  MHALF(1, 0, bv0r);  BVLOAD(bv0r, 48);
  MHALF(1, 1, bv1r);  BVLOAD(bv1r, 49);
  COMMIT(pfE, 0);     ISSUE_TAIL(pfE);
  BAR();
  // iter 24 (buf 0): commit pf(25), no issue
  MHALF(0, 0, bv0r);  BVLOAD(bv0r, 50);
  MHALF(0, 1, bv1r);  BVLOAD(bv1r, 51);
  COMMIT(pfO, 1);
  BAR();
  // iter 25 (buf 1): commit pf(26), no issue
  MHALF(1, 0, bv0r);  BVLOAD(bv0r, 52);
  MHALF(1, 1, bv1r);  BVLOAD(bv1r, 53);
  COMMIT(pfE, 0);
  BAR();
  // tail step 26 (buf 0)
  MHALF(0, 0, bv0r);
  MHALF(0, 1, bv1r);

  // ---- +conv_b, LN(256) across waves, relu -> t3 ----
  float sum[4][4], sq[4][4];
  #pragma unroll
  for (int mt=0;mt<4;++mt)
    #pragma unroll
    for (int r=0;r<4;++r){ sum[mt][r]=0.f; sq[mt][r]=0.f; }
  float biasv[4];
  #pragma unroll
  for (int nt=0;nt<4;++nt) biasv[nt] = cb[w*64+nt*16+lr];
  #pragma unroll
  for (int mt=0;mt<4;++mt)
    #pragma unroll
    for (int nt=0;nt<4;++nt)
      #pragma unroll
      for (int r=0;r<4;++r){
        float vv = acc1[mt][nt][r] + biasv[nt];
        acc1[mt][nt][r] = vv; sum[mt][r]+=vv; sq[mt][r]+=vv*vv;
      }
  #pragma unroll
  for (int m=1;m<16;m<<=1){
    #pragma unroll
    for (int mt=0;mt<4;++mt)
      #pragma unroll
      for (int r=0;r<4;++r){ sum[mt][r]+=__shfl_xor(sum[mt][r],m); sq[mt][r]+=__shfl_xor(sq[mt][r],m); }
  }
  if (lr==0){
    #pragma unroll
    for (int mt=0;mt<4;++mt)
      #pragma unroll
      for (int r=0;r<4;++r){
        const int row = mt*16+lh*4+r;
        ps[w][row]=sum[mt][r]; pq[w][row]=sq[mt][r];
      }
  }
  __syncthreads();     // also ends atile lifetime before t3 overwrite
  float meanv[4][4], rstdv[4][4];
  #pragma unroll
  for (int mt=0;mt<4;++mt)
    #pragma unroll
    for (int r=0;r<4;++r){
      const int row = mt*16+lh*4+r;
      const float S = ps[0][row]+ps[1][row]+ps[2][row]+ps[3][row];
      const float Q = pq[0][row]+pq[1][row]+pq[2][row]+pq[3][row];
      const float mu = S*(1.f/Hn);
      meanv[mt][r] = mu;
      rstdv[mt][r] = rsqrtf(fmaxf(Q*(1.f/Hn)-mu*mu, 0.f) + 1e-12f);
    }
  #pragma unroll
  for (int nt=0;nt<4;++nt){
    const int c2 = w*64+nt*16+lr;
    const float nw = n2w[c2], nb = n2b[c2];
    #pragma unroll
    for (int mt=0;mt<4;++mt)
      #pragma unroll
      for (int r=0;r<4;++r){
        const int row = mt*16+lh*4+r;
        float t = (acc1[mt][nt][r]-meanv[mt][r])*rstdv[mt][r]*nw + nb;
        t3[(row*256+c2) ^ ((row&7)<<3)] = f2b(fmaxf(t,0.f));
      }
  }
  __syncthreads();

  // ---- GEMM2 (two 64-col halves): y[64x512] = t3 @ lin2_W^T (K=256) ----
  #pragma unroll
  for (int h=0; h<2; ++h){
    f32x4 acc2[4][4];
    #pragma unroll
    for (int i=0;i<4;++i)
      #pragma unroll
      for (int j=0;j<4;++j) acc2[i][j] = f32x4{0.f,0.f,0.f,0.f};
    for (int kk=0;kk<8;++kk){
      bf16x8 a[4];
      #pragma unroll
      for (int mt=0;mt<4;++mt){
        const int row = mt*16+lr;
        a[mt] = ld8(&t3[(row*256 + kk*32 + lh*8) ^ ((row&7)<<3)]);
      }
      #pragma unroll
      for (int nt=0;nt<4;++nt){
        bf16x8 bb = ld8(W2f + (size_t)(((w*8 + h*4 + nt)*8) + kk)*512 + l*8);
        #pragma unroll
        for (int mt=0;mt<4;++mt) acc2[mt][nt] = mfma16(a[mt], bb, acc2[mt][nt]);
      }
    }
    #pragma unroll
    for (int nt=0;nt<4;++nt){
      const int c2 = w*128 + h*64 + nt*16 + lr;
      const float bias = bl2[c2];
      #pragma unroll
      for (int mt=0;mt<4;++mt){
        #pragma unroll
        for (int r=0;r<4;++r){
          const int mg = m0 + mt*16 + lh*4 + r;
          if (mg < Nn){
            const size_t off = ((size_t)b*Nn + mg)*Cn + c2;
            out[off] = acc2[mt][nt][r] + bias + x[off];
          }
        }
      }
    }
  }
  #undef ISSUE
  #undef ISSUE_TAIL
  #undef COMMIT
  #undef BVLOAD
  #undef MHALF
}

extern "C" void kernel_launch(void* const* d_in, const int* in_sizes, int n_in,
                              void* d_out, int out_size, void* d_ws, size_t ws_size,
                              hipStream_t stream){
  const float* x    = (const float*)d_in[0];
  const float* adj  = (const float*)d_in[1];
  const float* prw  = (const float*)d_in[2];
  const float* prb  = (const float*)d_in[3];
  const float* W1   = (const float*)d_in[4];
  const float* b1   = (const float*)d_in[5];
  const float* n1w  = (const float*)d_in[6];
  const float* n1b  = (const float*)d_in[7];
  const float* Wc   = (const float*)d_in[8];
  const float* cbv  = (const float*)d_in[9];
  const float* n2w  = (const float*)d_in[10];
  const float* n2b  = (const float*)d_in[11];
  const float* W2   = (const float*)d_in[12];
  const float* bl2  = (const float*)d_in[13];

  u16* ws    = (u16*)d_ws;
  u16* W1f   = ws;                           // 131072 u16
  u16* WcTf  = ws + 131072;                  // 65536
  u16* W2f   = ws + 131072 + 65536;          // 131072
  u16* supT  = ws + 131072 + 65536 + 131072; // 32*16*54*512 u16 (~28.3 MB)

  k_prep<<<dim3(160), dim3(256), 0, stream>>>(W1, Wc, W2, W1f, WcTf, W2f);
  k_stageA<<<dim3(MTA,Bn), dim3(256), 0, stream>>>(x, prw, prb, W1f, b1, n1w, n1b, WcTf, supT);
  k_stageB<<<dim3(MTB*Bn), dim3(256), 0, stream>>>(adj, supT, cbv, n2w, n2b, W2f, bl2, x, (float*)d_out);
}

// Round 8
// 399.941 us; speedup vs baseline: 1.1179x; 1.1179x over previous
//
#include <hip/hip_runtime.h>
#include <stdint.h>

#define Bn 32
#define Nn 1723
#define Cn 512
#define Hn 256
#define MTA 54    // ceil(1723/32): stage-A tiles == supT sub-steps
#define MTB 54    // stage-B row tiles (32 rows each)

typedef __bf16 bf16x8 __attribute__((ext_vector_type(8)));
typedef float f32x4 __attribute__((ext_vector_type(4)));
typedef unsigned short u16;

__device__ __forceinline__ u16 f2b(float f){
  union{float f; uint32_t i;} c; c.f=f; uint32_t u=c.i;
  u += 0x7fffu + ((u>>16)&1u);
  return (u16)(u>>16);
}
__device__ __forceinline__ bf16x8 ld8(const u16* p){
  union{ uint4 u; bf16x8 b; } c;
  c.u = *reinterpret_cast<const uint4*>(p);
  return c.b;
}
__device__ __forceinline__ f32x4 mfma16(bf16x8 a, bf16x8 b, f32x4 c){
  return __builtin_amdgcn_mfma_f32_16x16x32_bf16(a,b,c,0,0,0);
}
// lgkmcnt-only barrier: LDS writes visible, global loads stay in flight.
#define BAR() do{ asm volatile("s_waitcnt lgkmcnt(0)" ::: "memory"); \
                  __builtin_amdgcn_s_barrier(); \
                  asm volatile("" ::: "memory"); }while(0)

// ---- kernel 0: weights -> bf16 MFMA-fragment-major (validated R5) ----
__global__ __launch_bounds__(256) void k_prep(
    const float* __restrict__ W1, const float* __restrict__ Wc, const float* __restrict__ W2,
    u16* __restrict__ W1f, u16* __restrict__ WcTf, u16* __restrict__ W2f)
{
  const int t = blockIdx.x*256 + threadIdx.x;
  const int lane = t & 63, unit = t >> 6;
  const int lr = lane & 15, lh = lane >> 4;
  const float* src; u16* dst; int K, tile, kk; bool tr = false;
  if (unit < 256){ tile = unit>>4; kk = unit&15; src = W1; dst = W1f; K = 512; }
  else if (unit < 384){ int u = unit-256; tile = u>>3; kk = u&7; src = Wc; dst = WcTf; K = 256; tr = true; }
  else { int u = unit-384; tile = u>>3; kk = u&7; src = W2; dst = W2f; K = 256; }
  const int row = tile*16 + lr;
  const int k0 = kk*32 + lh*8;
  union{u16 s[8]; uint4 u;} o;
  #pragma unroll
  for (int j=0;j<8;++j){
    float v = tr ? src[(size_t)(k0+j)*256 + row] : src[(size_t)row*K + k0 + j];
    o.s[j] = f2b(v);
  }
  *reinterpret_cast<uint4*>(dst + (size_t)(tile*(K/32)+kk)*512 + lane*8) = o.u;
}

// ---------------- stage A (unchanged, validated R5/R6) ----------------
__global__ __launch_bounds__(256) void k_stageA(
    const float* __restrict__ x, const float* __restrict__ prw, const float* __restrict__ prb,
    const u16* __restrict__ W1f, const float* __restrict__ b1,
    const float* __restrict__ n1w, const float* __restrict__ n1b,
    const u16* __restrict__ WcTf, u16* __restrict__ supT)
{
  __shared__ u16 t1[32*512];
  __shared__ float ps[2][32], pq[2][32];
  u16* const t2 = t1;
  const int b = blockIdx.y;
  const int m0 = blockIdx.x*32;
  const int tid = threadIdx.x;
  const int w = tid>>6, l = tid&63, lr = l&15, lh = l>>4;
  const int wm = w>>1, wn = w&1;

  float pw[8], pb[8];
  #pragma unroll
  for (int j=0;j<8;++j){ pw[j]=prw[l*8+j]; pb[j]=prb[l*8+j]; }
  #pragma unroll
  for (int rr=0; rr<8; ++rr){
    const int rloc = w*8+rr;
    int rg = m0 + rloc; rg = rg < Nn ? rg : Nn-1;
    const float* src = x + ((size_t)b*Nn + rg)*Cn + l*8;
    float4 c0 = *reinterpret_cast<const float4*>(src);
    float4 c1 = *reinterpret_cast<const float4*>(src+4);
    float v[8] = {c0.x,c0.y,c0.z,c0.w,c1.x,c1.y,c1.z,c1.w};
    float s=0.f, q=0.f;
    #pragma unroll
    for (int j=0;j<8;++j){ s+=v[j]; q+=v[j]*v[j]; }
    #pragma unroll
    for (int m=1;m<64;m<<=1){ s += __shfl_xor(s,m); q += __shfl_xor(q,m); }
    const float mean = s*(1.f/Cn);
    const float rstd = rsqrtf(fmaxf(q*(1.f/Cn) - mean*mean, 0.f) + 1e-12f);
    union{uint4 u; u16 s[8];} ov;
    #pragma unroll
    for (int j=0;j<8;++j){
      float t = (v[j]-mean)*rstd*pw[j] + pb[j];
      ov.s[j] = f2b(fmaxf(t,0.f));
    }
    const int idx = (rloc*512 + l*8) ^ ((rloc&7)<<3);
    *reinterpret_cast<uint4*>(&t1[idx]) = ov.u;
  }
  __syncthreads();

  f32x4 acc[8];
  #pragma unroll
  for (int i=0;i<8;++i) acc[i] = f32x4{0.f,0.f,0.f,0.f};
  const int arow = wm*16 + lr;
  const int aswz = (arow&7)<<3;
  for (int kk=0; kk<16; ++kk){
    bf16x8 a = ld8(&t1[(arow*512 + kk*32 + lh*8) ^ aswz]);
    #pragma unroll
    for (int nt=0; nt<8; ++nt){
      bf16x8 bb = ld8(W1f + (size_t)(((wn*8+nt)*16 + kk))*512 + l*8);
      acc[nt] = mfma16(a, bb, acc[nt]);
    }
  }

  float sum[4]={0,0,0,0}, sq[4]={0,0,0,0};
  #pragma unroll
  for (int nt=0; nt<8; ++nt){
    const float bias = b1[wn*128+nt*16+lr];
    #pragma unroll
    for (int r=0;r<4;++r){
      float vv = acc[nt][r] + bias;
      acc[nt][r] = vv; sum[r]+=vv; sq[r]+=vv*vv;
    }
  }
  #pragma unroll
  for (int m=1;m<16;m<<=1){
    #pragma unroll
    for (int r=0;r<4;++r){ sum[r]+=__shfl_xor(sum[r],m); sq[r]+=__shfl_xor(sq[r],m); }
  }
  if (lr==0){
    #pragma unroll
    for (int r=0;r<4;++r){
      const int row = wm*16 + lh*4 + r;
      ps[wn][row]=sum[r]; pq[wn][row]=sq[r];
    }
  }
  __syncthreads();
  float mean[4], rstd[4];
  #pragma unroll
  for (int r=0;r<4;++r){
    const int row = wm*16 + lh*4 + r;
    const float S = ps[0][row]+ps[1][row];
    const float Q = pq[0][row]+pq[1][row];
    const float mu = S*(1.f/Hn);
    mean[r] = mu;
    rstd[r] = rsqrtf(fmaxf(Q*(1.f/Hn) - mu*mu, 0.f) + 1e-12f);
  }
  #pragma unroll
  for (int nt=0; nt<8; ++nt){
    const int col = wn*128+nt*16+lr;
    const float nw = n1w[col], nb = n1b[col];
    #pragma unroll
    for (int r=0;r<4;++r){
      const int row = wm*16 + lh*4 + r;
      float t = (acc[nt][r]-mean[r])*rstd[r]*nw + nb;
      t2[(row*256 + col) ^ ((row&7)<<3)] = f2b(fmaxf(t,0.f));
    }
  }
  __syncthreads();

  f32x4 acc2[8];
  #pragma unroll
  for (int i=0;i<8;++i) acc2[i] = f32x4{0.f,0.f,0.f,0.f};
  for (int kk=0; kk<8; ++kk){
    bf16x8 a = ld8(&t2[(arow*256 + kk*32 + lh*8) ^ aswz]);
    #pragma unroll
    for (int nt=0; nt<8; ++nt){
      bf16x8 bb = ld8(WcTf + (size_t)(((wn*8+nt)*8 + kk))*512 + l*8);
      acc2[nt] = mfma16(a, bb, acc2[nt]);
    }
  }

  const int off512 = (wm*2 + (lh>>1))*128 + lr*8 + (lh&1)*4;
  #pragma unroll
  for (int nt=0; nt<8; ++nt){
    const int htile = wn*8 + nt;
    const size_t base = ((size_t)(b*16 + htile)*MTA + blockIdx.x)*512 + off512;
    ushort4 o;
    o.x = f2b(acc2[nt][0]); o.y = f2b(acc2[nt][1]);
    o.z = f2b(acc2[nt][2]); o.w = f2b(acc2[nt][3]);
    *reinterpret_cast<ushort4*>(supT + base) = o;
  }
}

// ---------------- stage B: 32-row tiles, grid 1728, consumption-ordered pipeline ----------------
// grid = 8 XCD x (4 b x 54 tiles). 4 waves/block; wave w owns GEMM1 cols 64w..64w+63.
__global__ __launch_bounds__(256) void k_stageB(
    const float* __restrict__ adj, const u16* __restrict__ supT,
    const float* __restrict__ cb, const float* __restrict__ n2w, const float* __restrict__ n2b,
    const u16* __restrict__ W2f, const float* __restrict__ bl2,
    const float* __restrict__ x, float* __restrict__ out)
{
  __shared__ u16 atile[2][32*64];   // 8 KB
  __shared__ u16 t3[32*256];        // 16 KB
  __shared__ float ps[4][32], pq[4][32];
  const int bid = blockIdx.x;
  const int xcd = bid & 7, idx = bid >> 3;
  const int b = xcd*4 + (idx & 3);          // 4 consecutive b per XCD (supT L2-resident)
  const int m0 = (idx >> 2) * 32;
  const int tid = threadIdx.x, w = tid>>6, l = tid&63, lr = l&15, lh = l>>4;
  const int sc2 = tid & 31, sr0 = tid >> 5;

  const float* adjb = adj + (size_t)b*Nn*Nn;
  const u16* supb = supT + (size_t)b*16*MTA*512;

  int srow[4];
  #pragma unroll
  for (int i=0;i<4;++i){ int rg = m0 + sr0 + 8*i; srow[i] = rg<Nn?rg:Nn-1; }

  float2 pfE[4], pfO[4];
  bf16x8 bv0r[4], bv1r[4];
  f32x4 acc1[2][4];
  #pragma unroll
  for (int i=0;i<2;++i)
    #pragma unroll
    for (int j=0;j<4;++j) acc1[i][j] = f32x4{0.f,0.f,0.f,0.f};

  #define ISSUE(pf, s) do{                                              \
    const int kg = (s)*64 + sc2*2;  /* steps <=25: always in-bounds */  \
    _Pragma("unroll")                                                   \
    for (int i=0;i<4;++i)                                               \
      pf[i] = *reinterpret_cast<const float2*>(adjb + (size_t)srow[i]*Nn + kg); \
  }while(0)

  #define ISSUE_TAIL(pf) do{      /* step 26: guarded scalar loads */   \
    const int kg = 26*64 + sc2*2;                                       \
    _Pragma("unroll")                                                   \
    for (int i=0;i<4;++i){                                              \
      const float* p = adjb + (size_t)srow[i]*Nn;                       \
      pf[i].x = (kg   < Nn) ? p[kg]   : 0.f;                            \
      pf[i].y = (kg+1 < Nn) ? p[kg+1] : 0.f;                            \
    }                                                                   \
  }while(0)

  #define COMMIT(pf, buf) do{                                           \
    _Pragma("unroll")                                                   \
    for (int i=0;i<4;++i){                                              \
      const int row = sr0 + 8*i;                                        \
      uint32_t pk;                                                      \
      asm("v_cvt_pk_bf16_f32 %0, %1, %2" : "=v"(pk) : "v"(pf[i].x), "v"(pf[i].y)); \
      *reinterpret_cast<uint32_t*>(&atile[buf][(row*64 + sc2*2) ^ ((row&7)<<3)]) = pk; \
    }                                                                   \
  }while(0)

  #define BVLOAD(bvr, sub) do{                                          \
    _Pragma("unroll")                                                   \
    for (int nt=0;nt<4;++nt)                                            \
      bvr[nt] = ld8(supb + (size_t)((w*4+nt)*MTA + (sub))*512 + l*8);   \
  }while(0)

  #define MHALF(buf, half, bvr) do{                                     \
    _Pragma("unroll")                                                   \
    for (int mt=0;mt<2;++mt){                                           \
      const int row = mt*16+lr;                                         \
      bf16x8 a = ld8(&atile[buf][(row*64 + (half)*32 + lh*8) ^ ((row&7)<<3)]); \
      _Pragma("unroll")                                                 \
      for (int nt=0;nt<4;++nt) acc1[mt][nt] = mfma16(a, bvr[nt], acc1[mt][nt]); \
    }                                                                   \
  }while(0)

  // ---- prologue: pf(0),pf(1),pf(2) + bv(step0) in flight; atile[0] committed ----
  ISSUE(pfE, 0);
  BVLOAD(bv0r, 0); BVLOAD(bv1r, 1);
  ISSUE(pfO, 1);
  COMMIT(pfE, 0);       // waits pfE only (bv+pfO younger, stay in flight)
  ISSUE(pfE, 2);
  BAR();

  // ---- main loop: 11 pairs, steps 0..21 ----
  for (int sp=0; sp<11; ++sp){
    const int s = 2*sp;
    MHALF(0, 0, bv0r);  BVLOAD(bv0r, 2*s+2);
    MHALF(0, 1, bv1r);  BVLOAD(bv1r, 2*s+3);
    COMMIT(pfO, 1);     ISSUE(pfO, s+3);
    BAR();
    MHALF(1, 0, bv0r);  BVLOAD(bv0r, 2*s+4);
    MHALF(1, 1, bv1r);  BVLOAD(bv1r, 2*s+5);
    COMMIT(pfE, 0);     ISSUE(pfE, s+4);
    BAR();
  }
  // ---- peeled iters 22..25 ----
  MHALF(0, 0, bv0r);  BVLOAD(bv0r, 46);
  MHALF(0, 1, bv1r);  BVLOAD(bv1r, 47);
  COMMIT(pfO, 1);     ISSUE(pfO, 25);
  BAR();
  MHALF(1, 0, bv0r);  BVLOAD(bv0r, 48);
  MHALF(1, 1, bv1r);  BVLOAD(bv1r, 49);
  COMMIT(pfE, 0);     ISSUE_TAIL(pfE);
  BAR();
  MHALF(0, 0, bv0r);  BVLOAD(bv0r, 50);
  MHALF(0, 1, bv1r);  BVLOAD(bv1r, 51);
  COMMIT(pfO, 1);
  BAR();
  MHALF(1, 0, bv0r);  BVLOAD(bv0r, 52);
  MHALF(1, 1, bv1r);  BVLOAD(bv1r, 53);
  COMMIT(pfE, 0);
  BAR();
  MHALF(0, 0, bv0r);
  MHALF(0, 1, bv1r);

  // ---- +conv_b, LN(256) across waves, relu -> t3 ----
  float sum[2][4], sq[2][4];
  #pragma unroll
  for (int mt=0;mt<2;++mt)
    #pragma unroll
    for (int r=0;r<4;++r){ sum[mt][r]=0.f; sq[mt][r]=0.f; }
  float biasv[4];
  #pragma unroll
  for (int nt=0;nt<4;++nt) biasv[nt] = cb[w*64+nt*16+lr];
  #pragma unroll
  for (int mt=0;mt<2;++mt)
    #pragma unroll
    for (int nt=0;nt<4;++nt)
      #pragma unroll
      for (int r=0;r<4;++r){
        float vv = acc1[mt][nt][r] + biasv[nt];
        acc1[mt][nt][r] = vv; sum[mt][r]+=vv; sq[mt][r]+=vv*vv;
      }
  #pragma unroll
  for (int m=1;m<16;m<<=1){
    #pragma unroll
    for (int mt=0;mt<2;++mt)
      #pragma unroll
      for (int r=0;r<4;++r){ sum[mt][r]+=__shfl_xor(sum[mt][r],m); sq[mt][r]+=__shfl_xor(sq[mt][r],m); }
  }
  if (lr==0){
    #pragma unroll
    for (int mt=0;mt<2;++mt)
      #pragma unroll
      for (int r=0;r<4;++r){
        const int row = mt*16+lh*4+r;
        ps[w][row]=sum[mt][r]; pq[w][row]=sq[mt][r];
      }
  }
  __syncthreads();
  float meanv[2][4], rstdv[2][4];
  #pragma unroll
  for (int mt=0;mt<2;++mt)
    #pragma unroll
    for (int r=0;r<4;++r){
      const int row = mt*16+lh*4+r;
      const float S = ps[0][row]+ps[1][row]+ps[2][row]+ps[3][row];
      const float Q = pq[0][row]+pq[1][row]+pq[2][row]+pq[3][row];
      const float mu = S*(1.f/Hn);
      meanv[mt][r] = mu;
      rstdv[mt][r] = rsqrtf(fmaxf(Q*(1.f/Hn)-mu*mu, 0.f) + 1e-12f);
    }
  #pragma unroll
  for (int nt=0;nt<4;++nt){
    const int c2 = w*64+nt*16+lr;
    const float nw = n2w[c2], nb = n2b[c2];
    #pragma unroll
    for (int mt=0;mt<2;++mt)
      #pragma unroll
      for (int r=0;r<4;++r){
        const int row = mt*16+lh*4+r;
        float t = (acc1[mt][nt][r]-meanv[mt][r])*rstdv[mt][r]*nw + nb;
        t3[(row*256+c2) ^ ((row&7)<<3)] = f2b(fmaxf(t,0.f));
      }
  }
  __syncthreads();

  // ---- GEMM2 (two 64-col halves): y[32x512] = t3 @ lin2_W^T (K=256) ----
  #pragma unroll
  for (int h=0; h<2; ++h){
    f32x4 acc2[2][4];
    #pragma unroll
    for (int i=0;i<2;++i)
      #pragma unroll
      for (int j=0;j<4;++j) acc2[i][j] = f32x4{0.f,0.f,0.f,0.f};
    for (int kk=0;kk<8;++kk){
      bf16x8 a[2];
      #pragma unroll
      for (int mt=0;mt<2;++mt){
        const int row = mt*16+lr;
        a[mt] = ld8(&t3[(row*256 + kk*32 + lh*8) ^ ((row&7)<<3)]);
      }
      #pragma unroll
      for (int nt=0;nt<4;++nt){
        bf16x8 bb = ld8(W2f + (size_t)(((w*8 + h*4 + nt)*8) + kk)*512 + l*8);
        #pragma unroll
        for (int mt=0;mt<2;++mt) acc2[mt][nt] = mfma16(a[mt], bb, acc2[mt][nt]);
      }
    }
    #pragma unroll
    for (int nt=0;nt<4;++nt){
      const int c2 = w*128 + h*64 + nt*16 + lr;
      const float bias = bl2[c2];
      #pragma unroll
      for (int mt=0;mt<2;++mt){
        #pragma unroll
        for (int r=0;r<4;++r){
          const int mg = m0 + mt*16 + lh*4 + r;
          if (mg < Nn){
            const size_t off = ((size_t)b*Nn + mg)*Cn + c2;
            out[off] = acc2[mt][nt][r] + bias + x[off];
          }
        }
      }
    }
  }
  #undef ISSUE
  #undef ISSUE_TAIL
  #undef COMMIT
  #undef BVLOAD
  #undef MHALF
}

extern "C" void kernel_launch(void* const* d_in, const int* in_sizes, int n_in,
                              void* d_out, int out_size, void* d_ws, size_t ws_size,
                              hipStream_t stream){
  const float* x    = (const float*)d_in[0];
  const float* adj  = (const float*)d_in[1];
  const float* prw  = (const float*)d_in[2];
  const float* prb  = (const float*)d_in[3];
  const float* W1   = (const float*)d_in[4];
  const float* b1   = (const float*)d_in[5];
  const float* n1w  = (const float*)d_in[6];
  const float* n1b  = (const float*)d_in[7];
  const float* Wc   = (const float*)d_in[8];
  const float* cbv  = (const float*)d_in[9];
  const float* n2w  = (const float*)d_in[10];
  const float* n2b  = (const float*)d_in[11];
  const float* W2   = (const float*)d_in[12];
  const float* bl2  = (const float*)d_in[13];

  u16* ws    = (u16*)d_ws;
  u16* W1f   = ws;                           // 131072 u16
  u16* WcTf  = ws + 131072;                  // 65536
  u16* W2f   = ws + 131072 + 65536;          // 131072
  u16* supT  = ws + 131072 + 65536 + 131072; // 32*16*54*512 u16 (~28.3 MB)

  k_prep<<<dim3(160), dim3(256), 0, stream>>>(W1, Wc, W2, W1f, WcTf, W2f);
  k_stageA<<<dim3(MTA,Bn), dim3(256), 0, stream>>>(x, prw, prb, W1f, b1, n1w, n1b, WcTf, supT);
  k_stageB<<<dim3(MTB/2*Bn*2), dim3(256), 0, stream>>>(adj, supT, cbv, n2w, n2b, W2f, bl2, x, (float*)d_out);
}